// Round 1
// baseline (1208.467 us; speedup 1.0000x reference)
//
#include <hip/hip_runtime.h>
#include <cstdint>
#include <cstddef>

#define D_DIM 128

__device__ __forceinline__ float sigmoid_fast(float z) {
  // 1/(1+e^-z); v_exp + v_rcp. Plenty of precision for threshold 0.2.
  return __builtin_amdgcn_rcpf(1.0f + __expf(-z));
}

// Per-node precompute: Y = x@Wmn.T + (bmn+bme), G = x@Wgn.T + (bgn+bge),
// out_init = (sigmoid(x@Ws.T + bs)+0.5)*x + bias_other   (self layer + conv bias)
__global__ __launch_bounds__(256) void node_kernel(
    const float* __restrict__ x,
    const float* __restrict__ Wmn, const float* __restrict__ Wgn,
    const float* __restrict__ Ws,
    const float* __restrict__ bmn, const float* __restrict__ bme,
    const float* __restrict__ bgn, const float* __restrict__ bge,
    const float* __restrict__ bs, const float* __restrict__ bias_other,
    float* __restrict__ Y, float* __restrict__ G,
    float* __restrict__ out_init, int n) {
  __shared__ float xs[16][128];      // 8 KB: 16 nodes of x
  __shared__ float w0s[128][17];     // k-chunked W tiles, +1 pad
  __shared__ float w1s[128][17];
  __shared__ float w2s[128][17];
  const int t = threadIdx.x;
  const int tile = blockIdx.x * 16;

#pragma unroll
  for (int j = 0; j < 8; ++j) {
    int idx = t + j * 256;           // 0..2047
    int nl = idx >> 7, dd = idx & 127;
    int node = tile + nl;
    xs[nl][dd] = (node < n) ? x[(size_t)node * D_DIM + dd] : 0.0f;
  }

  float a0[8] = {0,0,0,0,0,0,0,0};
  float a1[8] = {0,0,0,0,0,0,0,0};
  float a2[8] = {0,0,0,0,0,0,0,0};
  const int d = t & 127;             // output dim
  const int nb = (t >> 7) * 8;       // node sub-block (0 or 8)

  for (int k0 = 0; k0 < 128; k0 += 16) {
    __syncthreads();
#pragma unroll
    for (int j = 0; j < 8; ++j) {
      int idx = t + j * 256;         // 0..2047 -> 128 rows x 16 cols
      int r = idx >> 4, c = idx & 15;
      w0s[r][c] = Wmn[r * D_DIM + k0 + c];
      w1s[r][c] = Wgn[r * D_DIM + k0 + c];
      w2s[r][c] = Ws[r * D_DIM + k0 + c];
    }
    __syncthreads();
#pragma unroll
    for (int kk = 0; kk < 16; ++kk) {
      float w0 = w0s[d][kk], w1 = w1s[d][kk], w2 = w2s[d][kk];
#pragma unroll
      for (int i = 0; i < 8; ++i) {
        float xv = xs[nb + i][k0 + kk];   // broadcast across wave
        a0[i] = fmaf(xv, w0, a0[i]);
        a1[i] = fmaf(xv, w1, a1[i]);
        a2[i] = fmaf(xv, w2, a2[i]);
      }
    }
  }

  const float bmv = bmn[d] + bme[d];
  const float bgv = bgn[d] + bge[d];
  const float bsv = bs[d];
  const float bov = bias_other[d];
#pragma unroll
  for (int i = 0; i < 8; ++i) {
    int node = tile + nb + i;
    if (node >= n) continue;
    size_t off = (size_t)node * D_DIM + d;
    Y[off] = a0[i] + bmv;
    G[off] = a1[i] + bgv;
    float sg = sigmoid_fast(a2[i] + bsv) + 0.5f;
    out_init[off] = sg * xs[nb + i][d] + bov;
  }
}

__global__ __launch_bounds__(256) void hist_kernel(
    const int* __restrict__ dst, int* __restrict__ counts, int E) {
  int e = blockIdx.x * blockDim.x + threadIdx.x;
  if (e < E) atomicAdd(&counts[dst[e]], 1);
}

// Single-block exclusive scan: counts[0..n) -> offsets[0..n], cursor copy.
__global__ __launch_bounds__(256) void scan_kernel(
    const int* __restrict__ counts, int* __restrict__ offsets,
    int* __restrict__ cursor, int n) {
  __shared__ int partials[257];
  int t = threadIdx.x;
  int seg = (n + 255) >> 8;
  int lo = min(t * seg, n), hi = min(lo + seg, n);
  int s = 0;
  for (int i = lo; i < hi; ++i) s += counts[i];
  partials[t] = s;
  __syncthreads();
  if (t == 0) {
    int run = 0;
    for (int i = 0; i < 256; ++i) { int c = partials[i]; partials[i] = run; run += c; }
    partials[256] = run;
  }
  __syncthreads();
  int run = partials[t];
  for (int i = lo; i < hi; ++i) {
    offsets[i] = run;
    cursor[i] = run;
    run += counts[i];
  }
  if (t == 255) offsets[n] = partials[256];
}

// Bucket edges by dst; pre-gather src and ef into dst-sorted order.
__global__ __launch_bounds__(256) void fill_kernel(
    const int* __restrict__ src, const int* __restrict__ dst,
    const float* __restrict__ ef, int* __restrict__ cursor,
    int* __restrict__ src_s, float* __restrict__ ef_s, int E) {
  int e = blockIdx.x * blockDim.x + threadIdx.x;
  if (e < E) {
    int p = atomicAdd(&cursor[dst[e]], 1);
    src_s[p] = src[e];
    ef_s[p] = ef[e];
  }
}

// One wave per destination node: acc = out_init; acc += sum msg*gate; relu; store.
__global__ __launch_bounds__(256) void gather_kernel(
    const float* __restrict__ Y, const float* __restrict__ G,
    const int* __restrict__ offsets,
    const int* __restrict__ src_s, const float* __restrict__ ef_s,
    const float* __restrict__ Wme, const float* __restrict__ Wge,
    float* __restrict__ out, int n_nodes) {
  int w = (int)((blockIdx.x * (unsigned)blockDim.x + threadIdx.x) >> 6);
  int lane = threadIdx.x & 63;
  if (w >= n_nodes) return;
  int beg = offsets[w], end = offsets[w + 1];
  float2 wme = *(const float2*)(Wme + 2 * lane);
  float2 wge = *(const float2*)(Wge + 2 * lane);
  float* op = out + (size_t)w * D_DIM + 2 * lane;
  float2 acc = *(const float2*)op;   // self + bias, written by node_kernel
#pragma unroll 4
  for (int p = beg; p < end; ++p) {
    int s = src_s[p];
    float f = ef_s[p];
    const float2 yv = *(const float2*)(Y + (size_t)s * D_DIM + 2 * lane);
    const float2 gv = *(const float2*)(G + (size_t)s * D_DIM + 2 * lane);
    float g0 = sigmoid_fast(fmaf(f, wge.x, gv.x)) - 0.5f;
    float g1 = sigmoid_fast(fmaf(f, wge.y, gv.y)) - 0.5f;
    acc.x += fmaf(f, wme.x, yv.x) * g0;
    acc.y += fmaf(f, wme.y, yv.y) * g1;
  }
  acc.x = fmaxf(acc.x, 0.0f);
  acc.y = fmaxf(acc.y, 0.0f);
  *(float2*)op = acc;
}

extern "C" void kernel_launch(void* const* d_in, const int* in_sizes, int n_in,
                              void* d_out, int out_size, void* d_ws, size_t ws_size,
                              hipStream_t stream) {
  const float* x_data  = (const float*)d_in[0];
  const float* x_task  = (const float*)d_in[1];
  const int*   src_dt  = (const int*)d_in[2];
  const int*   dst_dt  = (const int*)d_in[3];
  const float* ef_dt   = (const float*)d_in[4];
  const int*   src_td  = (const int*)d_in[5];
  const int*   dst_td  = (const int*)d_in[6];
  const float* ef_td   = (const float*)d_in[7];
  const float* Wmn_dt  = (const float*)d_in[8];
  const float* bmn_dt  = (const float*)d_in[9];
  const float* Wme_dt  = (const float*)d_in[10];
  const float* bme_dt  = (const float*)d_in[11];
  const float* Wgn_dt  = (const float*)d_in[12];
  const float* bgn_dt  = (const float*)d_in[13];
  const float* Wge_dt  = (const float*)d_in[14];
  const float* bge_dt  = (const float*)d_in[15];
  const float* bias_dt = (const float*)d_in[16];
  const float* Wmn_td  = (const float*)d_in[17];
  const float* bmn_td  = (const float*)d_in[18];
  const float* Wme_td  = (const float*)d_in[19];
  const float* bme_td  = (const float*)d_in[20];
  const float* Wgn_td  = (const float*)d_in[21];
  const float* bgn_td  = (const float*)d_in[22];
  const float* Wge_td  = (const float*)d_in[23];
  const float* bge_td  = (const float*)d_in[24];
  const float* bias_td = (const float*)d_in[25];
  const float* Ws_data = (const float*)d_in[26];
  const float* bs_data = (const float*)d_in[27];
  const float* Ws_task = (const float*)d_in[28];
  const float* bs_task = (const float*)d_in[29];
  float* out = (float*)d_out;

  const int N_DATA = in_sizes[0] / D_DIM;   // 100000
  const int N_TASK = in_sizes[1] / D_DIM;   // 20000
  const int E = in_sizes[2];                // 1000000

  // workspace layout
  char* ws = (char*)d_ws;
  size_t off = 0;
  auto alloc = [&](size_t bytes) { void* p = ws + off; off += (bytes + 255) & ~(size_t)255; return p; };
  float* Y_dt   = (float*)alloc((size_t)N_DATA * D_DIM * 4);
  float* G_dt   = (float*)alloc((size_t)N_DATA * D_DIM * 4);
  float* Y_td   = (float*)alloc((size_t)N_TASK * D_DIM * 4);
  float* G_td   = (float*)alloc((size_t)N_TASK * D_DIM * 4);
  int*   srcs_dt = (int*)alloc((size_t)E * 4);
  float* efs_dt  = (float*)alloc((size_t)E * 4);
  int*   srcs_td = (int*)alloc((size_t)E * 4);
  float* efs_td  = (float*)alloc((size_t)E * 4);
  int*   counts_dt = (int*)alloc((size_t)N_TASK * 4);      // dt conv: dst = task
  int*   counts_td = (int*)alloc((size_t)N_DATA * 4);      // td conv: dst = data
  int*   offs_dt   = (int*)alloc((size_t)(N_TASK + 1) * 4);
  int*   curs_dt   = (int*)alloc((size_t)N_TASK * 4);
  int*   offs_td   = (int*)alloc((size_t)(N_DATA + 1) * 4);
  int*   curs_td   = (int*)alloc((size_t)N_DATA * 4);
  (void)ws_size; (void)n_in; (void)out_size;

  // zero both histograms (contiguous region)
  hipMemsetAsync(counts_dt, 0, ((size_t)N_TASK * 4 + 255 & ~(size_t)255) + (size_t)N_DATA * 4, stream);

  // node precompute (also initializes d_out with self+conv-bias)
  node_kernel<<<(N_DATA + 15) / 16, 256, 0, stream>>>(
      x_data, Wmn_dt, Wgn_dt, Ws_data, bmn_dt, bme_dt, bgn_dt, bge_dt,
      bs_data, bias_td, Y_dt, G_dt, out, N_DATA);
  node_kernel<<<(N_TASK + 15) / 16, 256, 0, stream>>>(
      x_task, Wmn_td, Wgn_td, Ws_task, bmn_td, bme_td, bgn_td, bge_td,
      bs_task, bias_dt, Y_td, G_td, out + (size_t)N_DATA * D_DIM, N_TASK);

  int eb = (E + 255) / 256;
  hist_kernel<<<eb, 256, 0, stream>>>(dst_dt, counts_dt, E);
  hist_kernel<<<eb, 256, 0, stream>>>(dst_td, counts_td, E);
  scan_kernel<<<1, 256, 0, stream>>>(counts_dt, offs_dt, curs_dt, N_TASK);
  scan_kernel<<<1, 256, 0, stream>>>(counts_td, offs_td, curs_td, N_DATA);
  fill_kernel<<<eb, 256, 0, stream>>>(src_dt, dst_dt, ef_dt, curs_dt, srcs_dt, efs_dt, E);
  fill_kernel<<<eb, 256, 0, stream>>>(src_td, dst_td, ef_td, curs_td, srcs_td, efs_td, E);

  // dt conv -> task outputs; td conv -> data outputs. 4 waves/block.
  gather_kernel<<<(N_TASK + 3) / 4, 256, 0, stream>>>(
      Y_dt, G_dt, offs_dt, srcs_dt, efs_dt, Wme_dt, Wge_dt,
      out + (size_t)N_DATA * D_DIM, N_TASK);
  gather_kernel<<<(N_DATA + 3) / 4, 256, 0, stream>>>(
      Y_td, G_td, offs_td, srcs_td, efs_td, Wme_td, Wge_td,
      out, N_DATA);
}

// Round 2
// 702.459 us; speedup vs baseline: 1.7203x; 1.7203x over previous
//
#include <hip/hip_runtime.h>
#include <hip/hip_bf16.h>
#include <cstdint>
#include <cstddef>

#define D_DIM 128

typedef __attribute__((ext_vector_type(8))) short short8;
typedef __attribute__((ext_vector_type(4))) float f32x4;

__device__ __forceinline__ float sigmoid_fast(float z) {
  return __builtin_amdgcn_rcpf(1.0f + __expf(-z));
}

__device__ __forceinline__ unsigned short f2bf(float f) {
  union { float f; unsigned u; } v; v.f = f;
  unsigned r = v.u + 0x7FFF + ((v.u >> 16) & 1);   // RNE
  return (unsigned short)(r >> 16);
}
__device__ __forceinline__ float bf_lo(unsigned u) { return __uint_as_float(u << 16); }
__device__ __forceinline__ float bf_hi(unsigned u) { return __uint_as_float(u & 0xFFFF0000u); }

// Convert 6 [128x128] f32 weight matrices to bf16, contiguous in dst.
__global__ __launch_bounds__(256) void wconv_kernel(
    const float* __restrict__ s0, const float* __restrict__ s1, const float* __restrict__ s2,
    const float* __restrict__ s3, const float* __restrict__ s4, const float* __restrict__ s5,
    short* __restrict__ dst) {
  int idx = blockIdx.x * 256 + threadIdx.x;     // 96 blocks x 256 = 24576; 4096 threads/matrix
  int mat = idx >> 12;
  int pos = (idx & 4095) * 4;
  const float* s = (mat == 0) ? s0 : (mat == 1) ? s1 : (mat == 2) ? s2
                 : (mat == 3) ? s3 : (mat == 4) ? s4 : s5;
  float4 f = *(const float4*)(s + pos);
  short4 o;
  o.x = (short)f2bf(f.x); o.y = (short)f2bf(f.y);
  o.z = (short)f2bf(f.z); o.w = (short)f2bf(f.w);
  *(short4*)(dst + mat * 16384 + pos) = o;
}

// Per-node MFMA precompute:
//   Y = x@Wmn.T (+bmn+bme), G = x@Wgn.T (+bgn+bge)  -> packed bf16 YG[node][128] (lo=y, hi=g)
//   out_init = (sigmoid(x@Ws.T + bs)+0.5)*x + bias_other
// Block = 4 waves; wave computes 16 nodes x 128 dims via 8 n-tiles x 4 k-steps.
__global__ __launch_bounds__(256) void node_mfma_kernel(
    const float* __restrict__ x,
    const short* __restrict__ Wmnb, const short* __restrict__ Wgnb, const short* __restrict__ Wsb,
    const float* __restrict__ bmn, const float* __restrict__ bme,
    const float* __restrict__ bgn, const float* __restrict__ bge,
    const float* __restrict__ bs, const float* __restrict__ bias_other,
    unsigned int* __restrict__ YG, float* __restrict__ out_init, int n) {
  const int t = threadIdx.x;
  const int wave = t >> 6, lane = t & 63;
  const int q = lane >> 4, l15 = lane & 15;
  const int node_base = blockIdx.x * 64 + wave * 16;

  // A fragments: A[m=lane&15][k=q*8+j], 4 K-steps of 32
  short8 a[4];
  {
    int m = node_base + l15;
    int mc = m < n ? m : (n - 1);
    const float* xrow = x + (size_t)mc * D_DIM;
#pragma unroll
    for (int ks = 0; ks < 4; ++ks) {
      float4 f0 = *(const float4*)(xrow + ks * 32 + q * 8);
      float4 f1 = *(const float4*)(xrow + ks * 32 + q * 8 + 4);
      union { short8 s; __hip_bfloat162 h[4]; } u;
      u.h[0] = __float22bfloat162_rn({f0.x, f0.y});
      u.h[1] = __float22bfloat162_rn({f0.z, f0.w});
      u.h[2] = __float22bfloat162_rn({f1.x, f1.y});
      u.h[3] = __float22bfloat162_rn({f1.z, f1.w});
      a[ks] = u.s;
    }
  }

  f32x4 accY[8], accG[8], accS[8];
#pragma unroll
  for (int nt = 0; nt < 8; ++nt) { accY[nt] = {0,0,0,0}; accG[nt] = {0,0,0,0}; accS[nt] = {0,0,0,0}; }

#pragma unroll
  for (int nt = 0; nt < 8; ++nt) {
    const int row = nt * 16 + l15;          // B: n = lane&15, k = q*8+j; W row-major [n][k]
#pragma unroll
    for (int ks = 0; ks < 4; ++ks) {
      const int off = row * D_DIM + ks * 32 + q * 8;
      short8 bm = *(const short8*)(Wmnb + off);
      short8 bg = *(const short8*)(Wgnb + off);
      short8 bsw = *(const short8*)(Wsb + off);
      accY[nt] = __builtin_amdgcn_mfma_f32_16x16x32_bf16(a[ks], bm,  accY[nt], 0, 0, 0);
      accG[nt] = __builtin_amdgcn_mfma_f32_16x16x32_bf16(a[ks], bg,  accG[nt], 0, 0, 0);
      accS[nt] = __builtin_amdgcn_mfma_f32_16x16x32_bf16(a[ks], bsw, accS[nt], 0, 0, 0);
    }
  }

  // Epilogue: C/D layout col=lane&15, row=q*4+reg
#pragma unroll
  for (int nt = 0; nt < 8; ++nt) {
    int d = nt * 16 + l15;
    float bmv = bmn[d] + bme[d];
    float bgv = bgn[d] + bge[d];
    float bsv = bs[d];
    float bov = bias_other[d];
#pragma unroll
    for (int r = 0; r < 4; ++r) {
      int node = node_base + q * 4 + r;
      if (node >= n) continue;
      size_t off = (size_t)node * D_DIM + d;
      float y = accY[nt][r] + bmv;
      float g = accG[nt][r] + bgv;
      union { __hip_bfloat162 h; unsigned u; } p;
      p.h = __float22bfloat162_rn({y, g});
      YG[off] = p.u;
      float sg = sigmoid_fast(accS[nt][r] + bsv) + 0.5f;
      out_init[off] = sg * x[off] + bov;
    }
  }
}

__global__ __launch_bounds__(256) void hist_kernel(
    const int* __restrict__ dst, int* __restrict__ counts, int E) {
  int e = blockIdx.x * blockDim.x + threadIdx.x;
  if (e < E) atomicAdd(&counts[dst[e]], 1);
}

// Multi-block scan, phase A: block sums over 1024-count chunks.
__global__ __launch_bounds__(256) void scan_a_kernel(
    const int* __restrict__ counts, int* __restrict__ bsums, int n) {
  __shared__ int sh[256];
  int t = threadIdx.x;
  int i0 = blockIdx.x * 1024 + t * 4;
  int s = 0;
#pragma unroll
  for (int i = 0; i < 4; ++i) { int idx = i0 + i; if (idx < n) s += counts[idx]; }
  sh[t] = s; __syncthreads();
  for (int st = 128; st > 0; st >>= 1) { if (t < st) sh[t] += sh[t + st]; __syncthreads(); }
  if (t == 0) bsums[blockIdx.x] = sh[0];
}

// Phase C: block base from bsums, local Hillis-Steele scan, write offsets+cursor.
__global__ __launch_bounds__(256) void scan_c_kernel(
    const int* __restrict__ counts, const int* __restrict__ bsums,
    int* __restrict__ offsets, int* __restrict__ cursor, int n) {
  __shared__ int sh[256];
  int t = threadIdx.x;
  int s = 0;
  for (int i = t; i < (int)blockIdx.x; i += 256) s += bsums[i];
  sh[t] = s; __syncthreads();
  for (int st = 128; st > 0; st >>= 1) { if (t < st) sh[t] += sh[t + st]; __syncthreads(); }
  int base = sh[0];
  __syncthreads();

  int i0 = blockIdx.x * 1024 + t * 4;
  int c0 = (i0     < n) ? counts[i0]     : 0;
  int c1 = (i0 + 1 < n) ? counts[i0 + 1] : 0;
  int c2 = (i0 + 2 < n) ? counts[i0 + 2] : 0;
  int c3 = (i0 + 3 < n) ? counts[i0 + 3] : 0;
  int ls = c0 + c1 + c2 + c3;
  sh[t] = ls; __syncthreads();
  for (int st = 1; st < 256; st <<= 1) {
    int v = (t >= st) ? sh[t - st] : 0;
    __syncthreads();
    if (t >= st) sh[t] += v;
    __syncthreads();
  }
  int run = base + sh[t] - ls;
  if (i0     < n) { offsets[i0]     = run; cursor[i0]     = run; run += c0; }
  if (i0 + 1 < n) { offsets[i0 + 1] = run; cursor[i0 + 1] = run; run += c1; }
  if (i0 + 2 < n) { offsets[i0 + 2] = run; cursor[i0 + 2] = run; run += c2; }
  if (i0 + 3 < n) { offsets[i0 + 3] = run; cursor[i0 + 3] = run; run += c3; }
  if (blockIdx.x == gridDim.x - 1 && t == 255) offsets[n] = run;
}

// Bucket edges by dst; pack (src, ef) into one int2 in dst-sorted order.
__global__ __launch_bounds__(256) void fill_kernel(
    const int* __restrict__ src, const int* __restrict__ dst,
    const float* __restrict__ ef, int* __restrict__ cursor,
    int2* __restrict__ edata, int E) {
  int e = blockIdx.x * blockDim.x + threadIdx.x;
  if (e < E) {
    int p = atomicAdd(&cursor[dst[e]], 1);
    edata[p] = make_int2(src[e], __float_as_int(ef[e]));
  }
}

// One wave per destination node: acc = out_init; acc += sum msg*gate; relu; store.
__global__ __launch_bounds__(256) void gather_kernel(
    const unsigned int* __restrict__ YG,
    const int* __restrict__ offsets, const int2* __restrict__ edata,
    const float* __restrict__ Wme, const float* __restrict__ Wge,
    float* __restrict__ out, int n_nodes) {
  int w = (int)((blockIdx.x * 256u + threadIdx.x) >> 6);
  int lane = threadIdx.x & 63;
  if (w >= n_nodes) return;
  int beg = __builtin_amdgcn_readfirstlane(offsets[w]);
  int end = __builtin_amdgcn_readfirstlane(offsets[w + 1]);
  float2 wme = *(const float2*)(Wme + 2 * lane);
  float2 wge = *(const float2*)(Wge + 2 * lane);
  float* op = out + (size_t)w * D_DIM + 2 * lane;
  float2 acc = *(const float2*)op;   // self + conv-bias, from node_mfma_kernel
  for (int p = beg; p < end; ++p) {
    int2 e = edata[p];
    int s = e.x;
    float f = __int_as_float(e.y);
    uint2 yg = *(const uint2*)(YG + (size_t)s * D_DIM + 2 * lane);
    float y0 = bf_lo(yg.x), g0v = bf_hi(yg.x);
    float y1 = bf_lo(yg.y), g1v = bf_hi(yg.y);
    float g0 = sigmoid_fast(fmaf(f, wge.x, g0v)) - 0.5f;
    float g1 = sigmoid_fast(fmaf(f, wge.y, g1v)) - 0.5f;
    acc.x += fmaf(f, wme.x, y0) * g0;
    acc.y += fmaf(f, wme.y, y1) * g1;
  }
  acc.x = fmaxf(acc.x, 0.0f);
  acc.y = fmaxf(acc.y, 0.0f);
  *(float2*)op = acc;
}

extern "C" void kernel_launch(void* const* d_in, const int* in_sizes, int n_in,
                              void* d_out, int out_size, void* d_ws, size_t ws_size,
                              hipStream_t stream) {
  const float* x_data  = (const float*)d_in[0];
  const float* x_task  = (const float*)d_in[1];
  const int*   src_dt  = (const int*)d_in[2];
  const int*   dst_dt  = (const int*)d_in[3];
  const float* ef_dt   = (const float*)d_in[4];
  const int*   src_td  = (const int*)d_in[5];
  const int*   dst_td  = (const int*)d_in[6];
  const float* ef_td   = (const float*)d_in[7];
  const float* Wmn_dt  = (const float*)d_in[8];
  const float* bmn_dt  = (const float*)d_in[9];
  const float* Wme_dt  = (const float*)d_in[10];
  const float* bme_dt  = (const float*)d_in[11];
  const float* Wgn_dt  = (const float*)d_in[12];
  const float* bgn_dt  = (const float*)d_in[13];
  const float* Wge_dt  = (const float*)d_in[14];
  const float* bge_dt  = (const float*)d_in[15];
  const float* bias_dt = (const float*)d_in[16];
  const float* Wmn_td  = (const float*)d_in[17];
  const float* bmn_td  = (const float*)d_in[18];
  const float* Wme_td  = (const float*)d_in[19];
  const float* bme_td  = (const float*)d_in[20];
  const float* Wgn_td  = (const float*)d_in[21];
  const float* bgn_td  = (const float*)d_in[22];
  const float* Wge_td  = (const float*)d_in[23];
  const float* bge_td  = (const float*)d_in[24];
  const float* bias_td = (const float*)d_in[25];
  const float* Ws_data = (const float*)d_in[26];
  const float* bs_data = (const float*)d_in[27];
  const float* Ws_task = (const float*)d_in[28];
  const float* bs_task = (const float*)d_in[29];
  float* out = (float*)d_out;

  const int N_DATA = in_sizes[0] / D_DIM;   // 100000
  const int N_TASK = in_sizes[1] / D_DIM;   // 20000
  const int E = in_sizes[2];                // 1000000

  // workspace layout
  char* ws = (char*)d_ws;
  size_t off = 0;
  auto alloc = [&](size_t bytes) { void* p = ws + off; off += (bytes + 255) & ~(size_t)255; return p; };
  unsigned int* YG_dt = (unsigned int*)alloc((size_t)N_DATA * D_DIM * 4);   // packed bf16 (y,g)
  unsigned int* YG_td = (unsigned int*)alloc((size_t)N_TASK * D_DIM * 4);
  int2* edata_dt = (int2*)alloc((size_t)E * 8);
  int2* edata_td = (int2*)alloc((size_t)E * 8);
  int* counts    = (int*)alloc((size_t)(N_TASK + N_DATA) * 4);
  int* counts_dt = counts;            // dt conv: dst = task
  int* counts_td = counts + N_TASK;   // td conv: dst = data
  int* offs_dt   = (int*)alloc((size_t)(N_TASK + 1) * 4);
  int* curs_dt   = (int*)alloc((size_t)N_TASK * 4);
  int* offs_td   = (int*)alloc((size_t)(N_DATA + 1) * 4);
  int* curs_td   = (int*)alloc((size_t)N_DATA * 4);
  int* bsums_dt  = (int*)alloc(256 * 4);
  int* bsums_td  = (int*)alloc(256 * 4);
  short* Wb      = (short*)alloc((size_t)6 * 16384 * 2);  // bf16 weights
  (void)ws_size; (void)n_in; (void)out_size;

  hipMemsetAsync(counts, 0, (size_t)(N_TASK + N_DATA) * 4, stream);

  wconv_kernel<<<96, 256, 0, stream>>>(Wmn_dt, Wgn_dt, Ws_data, Wmn_td, Wgn_td, Ws_task, Wb);

  node_mfma_kernel<<<(N_DATA + 63) / 64, 256, 0, stream>>>(
      x_data, Wb, Wb + 16384, Wb + 32768,
      bmn_dt, bme_dt, bgn_dt, bge_dt, bs_data, bias_td,
      YG_dt, out, N_DATA);
  node_mfma_kernel<<<(N_TASK + 63) / 64, 256, 0, stream>>>(
      x_task, Wb + 3 * 16384, Wb + 4 * 16384, Wb + 5 * 16384,
      bmn_td, bme_td, bgn_td, bge_td, bs_task, bias_dt,
      YG_td, out + (size_t)N_DATA * D_DIM, N_TASK);

  int eb = (E + 255) / 256;
  hist_kernel<<<eb, 256, 0, stream>>>(dst_dt, counts_dt, E);
  hist_kernel<<<eb, 256, 0, stream>>>(dst_td, counts_td, E);

  int nbt = (N_TASK + 1023) / 1024, nbd = (N_DATA + 1023) / 1024;
  scan_a_kernel<<<nbt, 256, 0, stream>>>(counts_dt, bsums_dt, N_TASK);
  scan_a_kernel<<<nbd, 256, 0, stream>>>(counts_td, bsums_td, N_DATA);
  scan_c_kernel<<<nbt, 256, 0, stream>>>(counts_dt, bsums_dt, offs_dt, curs_dt, N_TASK);
  scan_c_kernel<<<nbd, 256, 0, stream>>>(counts_td, bsums_td, offs_td, curs_td, N_DATA);

  fill_kernel<<<eb, 256, 0, stream>>>(src_dt, dst_dt, ef_dt, curs_dt, edata_dt, E);
  fill_kernel<<<eb, 256, 0, stream>>>(src_td, dst_td, ef_td, curs_td, edata_td, E);

  gather_kernel<<<(N_TASK + 3) / 4, 256, 0, stream>>>(
      YG_dt, offs_dt, edata_dt, Wme_dt, Wge_dt, out + (size_t)N_DATA * D_DIM, N_TASK);
  gather_kernel<<<(N_DATA + 3) / 4, 256, 0, stream>>>(
      YG_td, offs_td, edata_td, Wme_td, Wge_td, out, N_DATA);
}

// Round 3
// 660.572 us; speedup vs baseline: 1.8294x; 1.0634x over previous
//
#include <hip/hip_runtime.h>
#include <hip/hip_bf16.h>
#include <cstdint>
#include <cstddef>

#define D_DIM 128

typedef __attribute__((ext_vector_type(8))) short short8;
typedef __attribute__((ext_vector_type(4))) float f32x4;

__device__ __forceinline__ float sigmoid_fast(float z) {
  return __builtin_amdgcn_rcpf(1.0f + __expf(-z));
}

__device__ __forceinline__ unsigned short f2bf(float f) {
  union { float f; unsigned u; } v; v.f = f;
  unsigned r = v.u + 0x7FFF + ((v.u >> 16) & 1);   // RNE
  return (unsigned short)(r >> 16);
}
__device__ __forceinline__ float bf_lo(unsigned u) { return __uint_as_float(u << 16); }
__device__ __forceinline__ float bf_hi(unsigned u) { return __uint_as_float(u & 0xFFFF0000u); }

// Convert 6 [128x128] f32 weight matrices to bf16, contiguous in dst.
__global__ __launch_bounds__(256) void wconv_kernel(
    const float* __restrict__ s0, const float* __restrict__ s1, const float* __restrict__ s2,
    const float* __restrict__ s3, const float* __restrict__ s4, const float* __restrict__ s5,
    short* __restrict__ dst) {
  int idx = blockIdx.x * 256 + threadIdx.x;     // 96 blocks x 256 = 24576; 4096 threads/matrix
  int mat = idx >> 12;
  int pos = (idx & 4095) * 4;
  const float* s = (mat == 0) ? s0 : (mat == 1) ? s1 : (mat == 2) ? s2
                 : (mat == 3) ? s3 : (mat == 4) ? s4 : s5;
  float4 f = *(const float4*)(s + pos);
  short4 o;
  o.x = (short)f2bf(f.x); o.y = (short)f2bf(f.y);
  o.z = (short)f2bf(f.z); o.w = (short)f2bf(f.w);
  *(short4*)(dst + mat * 16384 + pos) = o;
}

// Per-node MFMA precompute. Block = 4 waves covering 32 nodes.
// Wave (ng, h): nodes [base+ng*16, +16), dims [h, h+64). 48 accs/wave.
// Epilogue staged through LDS for fully-coalesced 16B stores.
__global__ __launch_bounds__(256) void node_mfma_kernel(
    const float* __restrict__ x,
    const short* __restrict__ Wmnb, const short* __restrict__ Wgnb, const short* __restrict__ Wsb,
    const float* __restrict__ bmn, const float* __restrict__ bme,
    const float* __restrict__ bgn, const float* __restrict__ bge,
    const float* __restrict__ bs, const float* __restrict__ bias_other,
    unsigned int* __restrict__ YG, float* __restrict__ out_init, int n) {
  __shared__ unsigned sh[32][132];               // 16.9 KB, reused across passes
  const int t = threadIdx.x;
  const int wave = t >> 6, lane = t & 63;
  const int q = lane >> 4, l15 = lane & 15;
  const int ng = wave >> 1;                      // node group 0/1
  const int h = (wave & 1) * 64;                 // dim half
  const int base_node = blockIdx.x * 32;
  const int node_base = base_node + ng * 16;

  // A fragments: A[m=lane&15][k=q*8+j], 4 K-steps of 32
  short8 a[4];
  {
    int m = node_base + l15;
    int mc = m < n ? m : (n - 1);
    const float* xrow = x + (size_t)mc * D_DIM;
#pragma unroll
    for (int ks = 0; ks < 4; ++ks) {
      float4 f0 = *(const float4*)(xrow + ks * 32 + q * 8);
      float4 f1 = *(const float4*)(xrow + ks * 32 + q * 8 + 4);
      union { short8 s; __hip_bfloat162 hh[4]; } u;
      u.hh[0] = __float22bfloat162_rn({f0.x, f0.y});
      u.hh[1] = __float22bfloat162_rn({f0.z, f0.w});
      u.hh[2] = __float22bfloat162_rn({f1.x, f1.y});
      u.hh[3] = __float22bfloat162_rn({f1.z, f1.w});
      a[ks] = u.s;
    }
  }

  f32x4 accY[4], accG[4], accS[4];
#pragma unroll
  for (int nt = 0; nt < 4; ++nt) { accY[nt] = {0,0,0,0}; accG[nt] = {0,0,0,0}; accS[nt] = {0,0,0,0}; }

#pragma unroll
  for (int nt = 0; nt < 4; ++nt) {
    const int row = h + nt * 16 + l15;           // B: n = lane&15, k = q*8+j
#pragma unroll
    for (int ks = 0; ks < 4; ++ks) {
      const int off = row * D_DIM + ks * 32 + q * 8;
      short8 bm  = *(const short8*)(Wmnb + off);
      short8 bg  = *(const short8*)(Wgnb + off);
      short8 bsw = *(const short8*)(Wsb + off);
      accY[nt] = __builtin_amdgcn_mfma_f32_16x16x32_bf16(a[ks], bm,  accY[nt], 0, 0, 0);
      accG[nt] = __builtin_amdgcn_mfma_f32_16x16x32_bf16(a[ks], bg,  accG[nt], 0, 0, 0);
      accS[nt] = __builtin_amdgcn_mfma_f32_16x16x32_bf16(a[ks], bsw, accS[nt], 0, 0, 0);
    }
  }

  // Pass 1: packed bf16 (y,g) -> LDS -> coalesced uint4 stores.
#pragma unroll
  for (int nt = 0; nt < 4; ++nt) {
    int d = h + nt * 16 + l15;
    float bmv = bmn[d] + bme[d];
    float bgv = bgn[d] + bge[d];
#pragma unroll
    for (int r = 0; r < 4; ++r) {
      union { __hip_bfloat162 hh; unsigned u; } pck;
      pck.hh = __float22bfloat162_rn({accY[nt][r] + bmv, accG[nt][r] + bgv});
      sh[ng * 16 + q * 4 + r][d] = pck.u;
    }
  }
  __syncthreads();
#pragma unroll
  for (int it = 0; it < 4; ++it) {
    int idx = (it * 256 + t) * 4;                // u32 index in [0, 4096)
    int nl = idx >> 7, dd = idx & 127;
    int node = base_node + nl;
    if (node < n)
      *(uint4*)(YG + (size_t)node * D_DIM + dd) = *(const uint4*)&sh[nl][dd];
  }
  __syncthreads();

  // Pass 2: self-gate -> LDS -> coalesced float4 out = sg*x + bias_other.
  float* shf = (float*)sh;
#pragma unroll
  for (int nt = 0; nt < 4; ++nt) {
    int d = h + nt * 16 + l15;
    float bsv = bs[d];
#pragma unroll
    for (int r = 0; r < 4; ++r)
      shf[(ng * 16 + q * 4 + r) * 132 + d] = sigmoid_fast(accS[nt][r] + bsv) + 0.5f;
  }
  __syncthreads();
#pragma unroll
  for (int it = 0; it < 4; ++it) {
    int idx = (it * 256 + t) * 4;
    int nl = idx >> 7, dd = idx & 127;
    int node = base_node + nl;
    if (node < n) {
      float4 xv = *(const float4*)(x + (size_t)node * D_DIM + dd);
      float4 bo = *(const float4*)(bias_other + dd);
      const float* sp = &shf[nl * 132 + dd];
      float4 o;
      o.x = sp[0] * xv.x + bo.x;
      o.y = sp[1] * xv.y + bo.y;
      o.z = sp[2] * xv.z + bo.z;
      o.w = sp[3] * xv.w + bo.w;
      *(float4*)(out_init + (size_t)node * D_DIM + dd) = o;
    }
  }
}

// Combined histogram over both convs (counts = [task | data]).
__global__ __launch_bounds__(256) void hist_kernel(
    const int* __restrict__ dst_dt, const int* __restrict__ dst_td,
    int* __restrict__ counts, int n_task, int E) {
  int e = blockIdx.x * 256 + threadIdx.x;
  if (e < E) {
    atomicAdd(&counts[dst_dt[e]], 1);
    atomicAdd(&counts[n_task + dst_td[e]], 1);
  }
}

// Multi-block scan, phase A: block sums over 1024-count chunks.
__global__ __launch_bounds__(256) void scan_a_kernel(
    const int* __restrict__ counts, int* __restrict__ bsums, int n) {
  __shared__ int sh[256];
  int t = threadIdx.x;
  int i0 = blockIdx.x * 1024 + t * 4;
  int s = 0;
#pragma unroll
  for (int i = 0; i < 4; ++i) { int idx = i0 + i; if (idx < n) s += counts[idx]; }
  sh[t] = s; __syncthreads();
  for (int st = 128; st > 0; st >>= 1) { if (t < st) sh[t] += sh[t + st]; __syncthreads(); }
  if (t == 0) bsums[blockIdx.x] = sh[0];
}

// Phase C: block base from bsums, local Hillis-Steele scan, write offsets+cursor.
__global__ __launch_bounds__(256) void scan_c_kernel(
    const int* __restrict__ counts, const int* __restrict__ bsums,
    int* __restrict__ offsets, int* __restrict__ cursor, int n) {
  __shared__ int sh[256];
  int t = threadIdx.x;
  int s = 0;
  for (int i = t; i < (int)blockIdx.x; i += 256) s += bsums[i];
  sh[t] = s; __syncthreads();
  for (int st = 128; st > 0; st >>= 1) { if (t < st) sh[t] += sh[t + st]; __syncthreads(); }
  int base = sh[0];
  __syncthreads();

  int i0 = blockIdx.x * 1024 + t * 4;
  int c0 = (i0     < n) ? counts[i0]     : 0;
  int c1 = (i0 + 1 < n) ? counts[i0 + 1] : 0;
  int c2 = (i0 + 2 < n) ? counts[i0 + 2] : 0;
  int c3 = (i0 + 3 < n) ? counts[i0 + 3] : 0;
  int ls = c0 + c1 + c2 + c3;
  sh[t] = ls; __syncthreads();
  for (int st = 1; st < 256; st <<= 1) {
    int v = (t >= st) ? sh[t - st] : 0;
    __syncthreads();
    if (t >= st) sh[t] += v;
    __syncthreads();
  }
  int run = base + sh[t] - ls;
  if (i0     < n) { offsets[i0]     = run; cursor[i0]     = run; run += c0; }
  if (i0 + 1 < n) { offsets[i0 + 1] = run; cursor[i0 + 1] = run; run += c1; }
  if (i0 + 2 < n) { offsets[i0 + 2] = run; cursor[i0 + 2] = run; run += c2; }
  if (i0 + 3 < n) { offsets[i0 + 3] = run; cursor[i0 + 3] = run; run += c3; }
  if (blockIdx.x == gridDim.x - 1 && t == 255) offsets[n] = run;
}

// Combined fill: bucket both convs' edges into one dst-sorted edata[2E].
__global__ __launch_bounds__(256) void fill_kernel(
    const int* __restrict__ src_dt, const int* __restrict__ dst_dt, const float* __restrict__ ef_dt,
    const int* __restrict__ src_td, const int* __restrict__ dst_td, const float* __restrict__ ef_td,
    int* __restrict__ cursor, int2* __restrict__ edata, int n_task, int E) {
  int e = blockIdx.x * 256 + threadIdx.x;
  if (e < E) {
    int p = atomicAdd(&cursor[dst_dt[e]], 1);
    edata[p] = make_int2(src_dt[e], __float_as_int(ef_dt[e]));
    int p2 = atomicAdd(&cursor[n_task + dst_td[e]], 1);
    edata[p2] = make_int2(src_td[e], __float_as_int(ef_td[e]));
  }
}

// Combined gather: wave w<n_task -> task dst (dt conv), else data dst (td conv).
__global__ __launch_bounds__(256) void gather_kernel(
    const unsigned* __restrict__ YG_dt, const unsigned* __restrict__ YG_td,
    const int* __restrict__ offsets, const int2* __restrict__ edata,
    const float* __restrict__ Wme_dt, const float* __restrict__ Wge_dt,
    const float* __restrict__ Wme_td, const float* __restrict__ Wge_td,
    float* __restrict__ out, int n_task, int n_data) {
  int w = (int)((blockIdx.x * 256u + threadIdx.x) >> 6);
  int lane = threadIdx.x & 63;
  if (w >= n_task + n_data) return;
  bool is_dt = w < n_task;
  const unsigned* YG = is_dt ? YG_dt : YG_td;
  const float* Wme = is_dt ? Wme_dt : Wme_td;
  const float* Wge = is_dt ? Wge_dt : Wge_td;
  size_t orow = is_dt ? (size_t)(n_data + w) : (size_t)(w - n_task);
  int beg = __builtin_amdgcn_readfirstlane(offsets[w]);
  int end = __builtin_amdgcn_readfirstlane(offsets[w + 1]);
  float2 wme = *(const float2*)(Wme + 2 * lane);
  float2 wge = *(const float2*)(Wge + 2 * lane);
  float* op = out + orow * D_DIM + 2 * lane;
  float2 acc = *(const float2*)op;               // self + conv-bias from node kernel
  int p = beg;
  for (; p + 2 <= end; p += 2) {                 // unroll-2: two YG rows in flight
    int2 e0 = edata[p], e1 = edata[p + 1];
    uint2 yg0 = *(const uint2*)(YG + (size_t)e0.x * D_DIM + 2 * lane);
    uint2 yg1 = *(const uint2*)(YG + (size_t)e1.x * D_DIM + 2 * lane);
    float f0 = __int_as_float(e0.y), f1 = __int_as_float(e1.y);
    float g0 = sigmoid_fast(fmaf(f0, wge.x, bf_hi(yg0.x))) - 0.5f;
    float g1 = sigmoid_fast(fmaf(f0, wge.y, bf_hi(yg0.y))) - 0.5f;
    acc.x += fmaf(f0, wme.x, bf_lo(yg0.x)) * g0;
    acc.y += fmaf(f0, wme.y, bf_lo(yg0.y)) * g1;
    float g2 = sigmoid_fast(fmaf(f1, wge.x, bf_hi(yg1.x))) - 0.5f;
    float g3 = sigmoid_fast(fmaf(f1, wge.y, bf_hi(yg1.y))) - 0.5f;
    acc.x += fmaf(f1, wme.x, bf_lo(yg1.x)) * g2;
    acc.y += fmaf(f1, wme.y, bf_lo(yg1.y)) * g3;
  }
  if (p < end) {
    int2 e0 = edata[p];
    uint2 yg0 = *(const uint2*)(YG + (size_t)e0.x * D_DIM + 2 * lane);
    float f0 = __int_as_float(e0.y);
    float g0 = sigmoid_fast(fmaf(f0, wge.x, bf_hi(yg0.x))) - 0.5f;
    float g1 = sigmoid_fast(fmaf(f0, wge.y, bf_hi(yg0.y))) - 0.5f;
    acc.x += fmaf(f0, wme.x, bf_lo(yg0.x)) * g0;
    acc.y += fmaf(f0, wme.y, bf_lo(yg0.y)) * g1;
  }
  acc.x = fmaxf(acc.x, 0.0f);
  acc.y = fmaxf(acc.y, 0.0f);
  *(float2*)op = acc;
}

extern "C" void kernel_launch(void* const* d_in, const int* in_sizes, int n_in,
                              void* d_out, int out_size, void* d_ws, size_t ws_size,
                              hipStream_t stream) {
  const float* x_data  = (const float*)d_in[0];
  const float* x_task  = (const float*)d_in[1];
  const int*   src_dt  = (const int*)d_in[2];
  const int*   dst_dt  = (const int*)d_in[3];
  const float* ef_dt   = (const float*)d_in[4];
  const int*   src_td  = (const int*)d_in[5];
  const int*   dst_td  = (const int*)d_in[6];
  const float* ef_td   = (const float*)d_in[7];
  const float* Wmn_dt  = (const float*)d_in[8];
  const float* bmn_dt  = (const float*)d_in[9];
  const float* Wme_dt  = (const float*)d_in[10];
  const float* bme_dt  = (const float*)d_in[11];
  const float* Wgn_dt  = (const float*)d_in[12];
  const float* bgn_dt  = (const float*)d_in[13];
  const float* Wge_dt  = (const float*)d_in[14];
  const float* bge_dt  = (const float*)d_in[15];
  const float* bias_dt = (const float*)d_in[16];
  const float* Wmn_td  = (const float*)d_in[17];
  const float* bmn_td  = (const float*)d_in[18];
  const float* Wme_td  = (const float*)d_in[19];
  const float* bme_td  = (const float*)d_in[20];
  const float* Wgn_td  = (const float*)d_in[21];
  const float* bgn_td  = (const float*)d_in[22];
  const float* Wge_td  = (const float*)d_in[23];
  const float* bge_td  = (const float*)d_in[24];
  const float* bias_td = (const float*)d_in[25];
  const float* Ws_data = (const float*)d_in[26];
  const float* bs_data = (const float*)d_in[27];
  const float* Ws_task = (const float*)d_in[28];
  const float* bs_task = (const float*)d_in[29];
  float* out = (float*)d_out;

  const int N_DATA = in_sizes[0] / D_DIM;   // 100000
  const int N_TASK = in_sizes[1] / D_DIM;   // 20000
  const int E = in_sizes[2];                // 1000000
  const int N_TOT = N_TASK + N_DATA;

  char* ws = (char*)d_ws;
  size_t off = 0;
  auto alloc = [&](size_t bytes) { void* p = ws + off; off += (bytes + 255) & ~(size_t)255; return p; };
  unsigned int* YG_dt = (unsigned int*)alloc((size_t)N_DATA * D_DIM * 4);   // packed bf16 (y,g)
  unsigned int* YG_td = (unsigned int*)alloc((size_t)N_TASK * D_DIM * 4);
  int2* edata   = (int2*)alloc((size_t)2 * E * 8);
  int*  counts  = (int*)alloc((size_t)N_TOT * 4);      // [task | data]
  int*  offs    = (int*)alloc((size_t)(N_TOT + 1) * 4);
  int*  curs    = (int*)alloc((size_t)N_TOT * 4);
  int*  bsums   = (int*)alloc(512 * 4);
  short* Wb     = (short*)alloc((size_t)6 * 16384 * 2);
  (void)ws_size; (void)n_in; (void)out_size;

  hipMemsetAsync(counts, 0, (size_t)N_TOT * 4, stream);

  wconv_kernel<<<96, 256, 0, stream>>>(Wmn_dt, Wgn_dt, Ws_data, Wmn_td, Wgn_td, Ws_task, Wb);

  node_mfma_kernel<<<(N_DATA + 31) / 32, 256, 0, stream>>>(
      x_data, Wb, Wb + 16384, Wb + 32768,
      bmn_dt, bme_dt, bgn_dt, bge_dt, bs_data, bias_td,
      YG_dt, out, N_DATA);
  node_mfma_kernel<<<(N_TASK + 31) / 32, 256, 0, stream>>>(
      x_task, Wb + 3 * 16384, Wb + 4 * 16384, Wb + 5 * 16384,
      bmn_td, bme_td, bgn_td, bge_td, bs_task, bias_dt,
      YG_td, out + (size_t)N_DATA * D_DIM, N_TASK);

  int eb = (E + 255) / 256;
  hist_kernel<<<eb, 256, 0, stream>>>(dst_dt, dst_td, counts, N_TASK, E);

  int nb = (N_TOT + 1023) / 1024;
  scan_a_kernel<<<nb, 256, 0, stream>>>(counts, bsums, N_TOT);
  scan_c_kernel<<<nb, 256, 0, stream>>>(counts, bsums, offs, curs, N_TOT);

  fill_kernel<<<eb, 256, 0, stream>>>(src_dt, dst_dt, ef_dt, src_td, dst_td, ef_td,
                                      curs, edata, N_TASK, E);

  gather_kernel<<<(N_TOT + 3) / 4, 256, 0, stream>>>(
      YG_dt, YG_td, offs, edata, Wme_dt, Wge_dt, Wme_td, Wge_td, out, N_TASK, N_DATA);
}

// Round 4
// 495.988 us; speedup vs baseline: 2.4365x; 1.3318x over previous
//
#include <hip/hip_runtime.h>
#include <hip/hip_bf16.h>
#include <cstdint>
#include <cstddef>

#define D_DIM 128

typedef __attribute__((ext_vector_type(8))) short short8;
typedef __attribute__((ext_vector_type(4))) float f32x4;

__device__ __forceinline__ float sigmoid_fast(float z) {
  return __builtin_amdgcn_rcpf(1.0f + __expf(-z));
}

__device__ __forceinline__ unsigned short f2bf(float f) {
  union { float f; unsigned u; } v; v.f = f;
  unsigned r = v.u + 0x7FFF + ((v.u >> 16) & 1);   // RNE
  return (unsigned short)(r >> 16);
}
__device__ __forceinline__ float bf_lo(unsigned u) { return __uint_as_float(u << 16); }
__device__ __forceinline__ float bf_hi(unsigned u) { return __uint_as_float(u & 0xFFFF0000u); }

// Convert 6 [128x128] f32 weight matrices to bf16, contiguous in dst.
__global__ __launch_bounds__(256) void wconv_kernel(
    const float* __restrict__ s0, const float* __restrict__ s1, const float* __restrict__ s2,
    const float* __restrict__ s3, const float* __restrict__ s4, const float* __restrict__ s5,
    short* __restrict__ dst) {
  int idx = blockIdx.x * 256 + threadIdx.x;
  int mat = idx >> 12;
  int pos = (idx & 4095) * 4;
  const float* s = (mat == 0) ? s0 : (mat == 1) ? s1 : (mat == 2) ? s2
                 : (mat == 3) ? s3 : (mat == 4) ? s4 : s5;
  float4 f = *(const float4*)(s + pos);
  short4 o;
  o.x = (short)f2bf(f.x); o.y = (short)f2bf(f.y);
  o.z = (short)f2bf(f.z); o.w = (short)f2bf(f.w);
  *(short4*)(dst + mat * 16384 + pos) = o;
}

// Per-node MFMA precompute. Block = 4 waves covering 32 nodes.
__global__ __launch_bounds__(256) void node_mfma_kernel(
    const float* __restrict__ x,
    const short* __restrict__ Wmnb, const short* __restrict__ Wgnb, const short* __restrict__ Wsb,
    const float* __restrict__ bmn, const float* __restrict__ bme,
    const float* __restrict__ bgn, const float* __restrict__ bge,
    const float* __restrict__ bs, const float* __restrict__ bias_other,
    unsigned int* __restrict__ YG, float* __restrict__ out_init, int n) {
  __shared__ unsigned sh[32][132];
  const int t = threadIdx.x;
  const int wave = t >> 6, lane = t & 63;
  const int q = lane >> 4, l15 = lane & 15;
  const int ng = wave >> 1;
  const int h = (wave & 1) * 64;
  const int base_node = blockIdx.x * 32;
  const int node_base = base_node + ng * 16;

  short8 a[4];
  {
    int m = node_base + l15;
    int mc = m < n ? m : (n - 1);
    const float* xrow = x + (size_t)mc * D_DIM;
#pragma unroll
    for (int ks = 0; ks < 4; ++ks) {
      float4 f0 = *(const float4*)(xrow + ks * 32 + q * 8);
      float4 f1 = *(const float4*)(xrow + ks * 32 + q * 8 + 4);
      union { short8 s; __hip_bfloat162 hh[4]; } u;
      u.hh[0] = __float22bfloat162_rn({f0.x, f0.y});
      u.hh[1] = __float22bfloat162_rn({f0.z, f0.w});
      u.hh[2] = __float22bfloat162_rn({f1.x, f1.y});
      u.hh[3] = __float22bfloat162_rn({f1.z, f1.w});
      a[ks] = u.s;
    }
  }

  f32x4 accY[4], accG[4], accS[4];
#pragma unroll
  for (int nt = 0; nt < 4; ++nt) { accY[nt] = {0,0,0,0}; accG[nt] = {0,0,0,0}; accS[nt] = {0,0,0,0}; }

#pragma unroll
  for (int nt = 0; nt < 4; ++nt) {
    const int row = h + nt * 16 + l15;
#pragma unroll
    for (int ks = 0; ks < 4; ++ks) {
      const int off = row * D_DIM + ks * 32 + q * 8;
      short8 bm  = *(const short8*)(Wmnb + off);
      short8 bg  = *(const short8*)(Wgnb + off);
      short8 bsw = *(const short8*)(Wsb + off);
      accY[nt] = __builtin_amdgcn_mfma_f32_16x16x32_bf16(a[ks], bm,  accY[nt], 0, 0, 0);
      accG[nt] = __builtin_amdgcn_mfma_f32_16x16x32_bf16(a[ks], bg,  accG[nt], 0, 0, 0);
      accS[nt] = __builtin_amdgcn_mfma_f32_16x16x32_bf16(a[ks], bsw, accS[nt], 0, 0, 0);
    }
  }

#pragma unroll
  for (int nt = 0; nt < 4; ++nt) {
    int d = h + nt * 16 + l15;
    float bmv = bmn[d] + bme[d];
    float bgv = bgn[d] + bge[d];
#pragma unroll
    for (int r = 0; r < 4; ++r) {
      union { __hip_bfloat162 hh; unsigned u; } pck;
      pck.hh = __float22bfloat162_rn({accY[nt][r] + bmv, accG[nt][r] + bgv});
      sh[ng * 16 + q * 4 + r][d] = pck.u;
    }
  }
  __syncthreads();
#pragma unroll
  for (int it = 0; it < 4; ++it) {
    int idx = (it * 256 + t) * 4;
    int nl = idx >> 7, dd = idx & 127;
    int node = base_node + nl;
    if (node < n)
      *(uint4*)(YG + (size_t)node * D_DIM + dd) = *(const uint4*)&sh[nl][dd];
  }
  __syncthreads();

  float* shf = (float*)sh;
#pragma unroll
  for (int nt = 0; nt < 4; ++nt) {
    int d = h + nt * 16 + l15;
    float bsv = bs[d];
#pragma unroll
    for (int r = 0; r < 4; ++r)
      shf[(ng * 16 + q * 4 + r) * 132 + d] = sigmoid_fast(accS[nt][r] + bsv) + 0.5f;
  }
  __syncthreads();
#pragma unroll
  for (int it = 0; it < 4; ++it) {
    int idx = (it * 256 + t) * 4;
    int nl = idx >> 7, dd = idx & 127;
    int node = base_node + nl;
    if (node < n) {
      float4 xv = *(const float4*)(x + (size_t)node * D_DIM + dd);
      float4 bo = *(const float4*)(bias_other + dd);
      const float* sp = &shf[nl * 132 + dd];
      float4 o;
      o.x = sp[0] * xv.x + bo.x;
      o.y = sp[1] * xv.y + bo.y;
      o.z = sp[2] * xv.z + bo.z;
      o.w = sp[3] * xv.w + bo.w;
      *(float4*)(out_init + (size_t)node * D_DIM + dd) = o;
    }
  }
}

// ---------- two-level counting sort of edges by combined dst ----------
// Combined dst c: task edges c=dst_dt in [0,n_task); data edges c=n_task+dst_td.
// Coarse buckets: task 64 dsts/bucket (nbt buckets), data 256 dsts/bucket.

// Pass 0: coarse histogram with LDS pre-aggregation.
__global__ __launch_bounds__(256) void hist0_kernel(
    const int* __restrict__ dst_dt, const int* __restrict__ dst_td,
    int* __restrict__ ghist, int nbt, int NB, int E) {
  __shared__ int lh[768];
  int t = threadIdx.x;
  lh[t] = 0; lh[t + 256] = 0; lh[t + 512] = 0;
  __syncthreads();
  for (int i = blockIdx.x * 256 + t; i < E; i += gridDim.x * 256) {
    atomicAdd(&lh[dst_dt[i] >> 6], 1);
    atomicAdd(&lh[nbt + (dst_td[i] >> 8)], 1);
  }
  __syncthreads();
#pragma unroll
  for (int k = 0; k < 3; ++k) {
    int b = t + k * 256;
    int c = lh[b];
    if (b < NB && c) atomicAdd(&ghist[b], c);
  }
}

// Scan 704 bucket counts -> bases + cursors; write offsets sentinel.
__global__ __launch_bounds__(256) void bucket_scan_kernel(
    const int* __restrict__ ghist, int* __restrict__ bbase, int* __restrict__ bcur,
    int* __restrict__ offsets, int NB, int n_tot) {
  __shared__ int sc[256];
  int t = threadIdx.x;
  int i0 = t * 3;
  int c0 = (i0     < NB) ? ghist[i0]     : 0;
  int c1 = (i0 + 1 < NB) ? ghist[i0 + 1] : 0;
  int c2 = (i0 + 2 < NB) ? ghist[i0 + 2] : 0;
  int tot = c0 + c1 + c2;
  sc[t] = tot; __syncthreads();
  for (int s = 1; s < 256; s <<= 1) {
    int u = (t >= s) ? sc[t - s] : 0;
    __syncthreads(); sc[t] += u; __syncthreads();
  }
  int base = sc[t] - tot;
  if (i0     < NB) { bbase[i0]     = base;           bcur[i0]     = base; }
  if (i0 + 1 < NB) { bbase[i0 + 1] = base + c0;      bcur[i0 + 1] = base + c0; }
  if (i0 + 2 < NB) { bbase[i0 + 2] = base + c0 + c1; bcur[i0 + 2] = base + c0 + c1; }
  if (t == 255) { bbase[NB] = sc[255]; offsets[n_tot] = sc[255]; }
}

// Pass A: coarse partition. Block handles 4096 edges of each list; per-bucket
// contiguous runs reserved with one global atomicAdd. Entry = {src, ef_hi24|loc8}.
__global__ __launch_bounds__(256) void sort_a_kernel(
    const int* __restrict__ src_dt, const int* __restrict__ dst_dt, const float* __restrict__ ef_dt,
    const int* __restrict__ src_td, const int* __restrict__ dst_td, const float* __restrict__ ef_td,
    int* __restrict__ bcur, int2* __restrict__ eA, int nbt, int NB, int E) {
  __shared__ int lh[768];
  __shared__ int lcur[768];
  int t = threadIdx.x;
  lh[t] = 0; lh[t + 256] = 0; lh[t + 512] = 0;
  __syncthreads();
  int e0 = blockIdx.x * 4096;
  int e1 = min(E, e0 + 4096);
  for (int i = e0 + t; i < e1; i += 256) {
    atomicAdd(&lh[dst_dt[i] >> 6], 1);
    atomicAdd(&lh[nbt + (dst_td[i] >> 8)], 1);
  }
  __syncthreads();
#pragma unroll
  for (int k = 0; k < 3; ++k) {
    int b = t + k * 256;
    int c = lh[b];
    if (b < NB && c) lcur[b] = atomicAdd(&bcur[b], c);
  }
  __syncthreads();
  for (int i = e0 + t; i < e1; i += 256) {
    int c = dst_dt[i];
    int bkt = c >> 6;
    int pos = atomicAdd(&lcur[bkt], 1);
    eA[pos] = make_int2(src_dt[i],
        (int)((__float_as_uint(ef_dt[i]) & 0xFFFFFF00u) | (unsigned)(c & 63)));
    int cd = dst_td[i];
    int bkt2 = nbt + (cd >> 8);
    int pos2 = atomicAdd(&lcur[bkt2], 1);
    eA[pos2] = make_int2(src_td[i],
        (int)((__float_as_uint(ef_td[i]) & 0xFFFFFF00u) | (unsigned)(cd & 255)));
  }
}

// Pass B: one block per bucket. 256-bin hist+scan; write final per-dst offsets;
// scatter entries within the bucket's contiguous (L2-resident) region.
__global__ __launch_bounds__(256) void sort_b_kernel(
    const int2* __restrict__ eA, const int* __restrict__ bbase,
    int* __restrict__ offsets, int2* __restrict__ eB,
    int nbt, int n_task, int n_tot) {
  __shared__ int lh[256], sc[256], lcur[256];
  int b = blockIdx.x, t = threadIdx.x;
  int base = bbase[b];
  int cnt = bbase[b + 1] - base;
  int c0, nloc;
  if (b < nbt) { c0 = b << 6; nloc = min(64, n_task - c0); }
  else { c0 = n_task + ((b - nbt) << 8); nloc = min(256, n_tot - c0); }
  lh[t] = 0; __syncthreads();
  for (int i = base + t; i < base + cnt; i += 256)
    atomicAdd(&lh[((unsigned)eA[i].y) & 255u], 1);
  __syncthreads();
  int v = lh[t];
  sc[t] = v; __syncthreads();
  for (int s = 1; s < 256; s <<= 1) {
    int u = (t >= s) ? sc[t - s] : 0;
    __syncthreads(); sc[t] += u; __syncthreads();
  }
  int ex = sc[t] - v;
  lcur[t] = base + ex;
  if (t < nloc) offsets[c0 + t] = base + ex;
  __syncthreads();
  for (int i = base + t; i < base + cnt; i += 256) {
    int2 e = eA[i];
    int pos = atomicAdd(&lcur[((unsigned)e.y) & 255u], 1);
    eB[pos] = e;
  }
}

// Combined gather: wave w<n_task -> task dst (dt conv), else data dst (td conv).
__device__ __forceinline__ void gstep(float2& acc, int2 e, const unsigned* __restrict__ YG,
                                      int lane, float2 wme, float2 wge) {
  uint2 yg = *(const uint2*)(YG + (size_t)e.x * D_DIM + 2 * lane);
  float f = __int_as_float(e.y & (int)0xFFFFFF00);
  float g0 = sigmoid_fast(fmaf(f, wge.x, bf_hi(yg.x))) - 0.5f;
  float g1 = sigmoid_fast(fmaf(f, wge.y, bf_hi(yg.y))) - 0.5f;
  acc.x += fmaf(f, wme.x, bf_lo(yg.x)) * g0;
  acc.y += fmaf(f, wme.y, bf_lo(yg.y)) * g1;
}

__global__ __launch_bounds__(256) void gather_kernel(
    const unsigned* __restrict__ YG_dt, const unsigned* __restrict__ YG_td,
    const int* __restrict__ offsets, const int2* __restrict__ edata,
    const float* __restrict__ Wme_dt, const float* __restrict__ Wge_dt,
    const float* __restrict__ Wme_td, const float* __restrict__ Wge_td,
    float* __restrict__ out, int n_task, int n_data) {
  int w = (int)((blockIdx.x * 256u + threadIdx.x) >> 6);
  int lane = threadIdx.x & 63;
  if (w >= n_task + n_data) return;
  bool is_dt = w < n_task;
  const unsigned* YG = is_dt ? YG_dt : YG_td;
  const float* Wme = is_dt ? Wme_dt : Wme_td;
  const float* Wge = is_dt ? Wge_dt : Wge_td;
  size_t orow = is_dt ? (size_t)(n_data + w) : (size_t)(w - n_task);
  int beg = __builtin_amdgcn_readfirstlane(offsets[w]);
  int end = __builtin_amdgcn_readfirstlane(offsets[w + 1]);
  float2 wme = *(const float2*)(Wme + 2 * lane);
  float2 wge = *(const float2*)(Wge + 2 * lane);
  float* op = out + orow * D_DIM + 2 * lane;
  float2 acc = *(const float2*)op;
  int p = beg;
  for (; p + 4 <= end; p += 4) {
    int2 e0 = edata[p], e1 = edata[p + 1], e2 = edata[p + 2], e3 = edata[p + 3];
    gstep(acc, e0, YG, lane, wme, wge);
    gstep(acc, e1, YG, lane, wme, wge);
    gstep(acc, e2, YG, lane, wme, wge);
    gstep(acc, e3, YG, lane, wme, wge);
  }
  for (; p < end; ++p) gstep(acc, edata[p], YG, lane, wme, wge);
  acc.x = fmaxf(acc.x, 0.0f);
  acc.y = fmaxf(acc.y, 0.0f);
  *(float2*)op = acc;
}

extern "C" void kernel_launch(void* const* d_in, const int* in_sizes, int n_in,
                              void* d_out, int out_size, void* d_ws, size_t ws_size,
                              hipStream_t stream) {
  const float* x_data  = (const float*)d_in[0];
  const float* x_task  = (const float*)d_in[1];
  const int*   src_dt  = (const int*)d_in[2];
  const int*   dst_dt  = (const int*)d_in[3];
  const float* ef_dt   = (const float*)d_in[4];
  const int*   src_td  = (const int*)d_in[5];
  const int*   dst_td  = (const int*)d_in[6];
  const float* ef_td   = (const float*)d_in[7];
  const float* Wmn_dt  = (const float*)d_in[8];
  const float* bmn_dt  = (const float*)d_in[9];
  const float* Wme_dt  = (const float*)d_in[10];
  const float* bme_dt  = (const float*)d_in[11];
  const float* Wgn_dt  = (const float*)d_in[12];
  const float* bgn_dt  = (const float*)d_in[13];
  const float* Wge_dt  = (const float*)d_in[14];
  const float* bge_dt  = (const float*)d_in[15];
  const float* bias_dt = (const float*)d_in[16];
  const float* Wmn_td  = (const float*)d_in[17];
  const float* bmn_td  = (const float*)d_in[18];
  const float* Wme_td  = (const float*)d_in[19];
  const float* bme_td  = (const float*)d_in[20];
  const float* Wgn_td  = (const float*)d_in[21];
  const float* bgn_td  = (const float*)d_in[22];
  const float* Wge_td  = (const float*)d_in[23];
  const float* bge_td  = (const float*)d_in[24];
  const float* bias_td = (const float*)d_in[25];
  const float* Ws_data = (const float*)d_in[26];
  const float* bs_data = (const float*)d_in[27];
  const float* Ws_task = (const float*)d_in[28];
  const float* bs_task = (const float*)d_in[29];
  float* out = (float*)d_out;

  const int N_DATA = in_sizes[0] / D_DIM;   // 100000
  const int N_TASK = in_sizes[1] / D_DIM;   // 20000
  const int E = in_sizes[2];                // 1000000
  const int N_TOT = N_TASK + N_DATA;
  const int NBT = (N_TASK + 63) >> 6;       // 313 task buckets (64 dsts each)
  const int NBD = (N_DATA + 255) >> 8;      // 391 data buckets (256 dsts each)
  const int NB = NBT + NBD;                 // 704

  char* ws = (char*)d_ws;
  size_t off = 0;
  auto alloc = [&](size_t bytes) { void* p = ws + off; off += (bytes + 255) & ~(size_t)255; return p; };
  unsigned int* YG_dt = (unsigned int*)alloc((size_t)N_DATA * D_DIM * 4);
  unsigned int* YG_td = (unsigned int*)alloc((size_t)N_TASK * D_DIM * 4);
  int2* eA     = (int2*)alloc((size_t)2 * E * 8);
  int2* eB     = (int2*)alloc((size_t)2 * E * 8);
  int*  offs   = (int*)alloc((size_t)(N_TOT + 1) * 4);
  int*  ghist  = (int*)alloc(768 * 4);
  int*  bbase  = (int*)alloc(768 * 4);
  int*  bcur   = (int*)alloc(768 * 4);
  short* Wb    = (short*)alloc((size_t)6 * 16384 * 2);
  (void)ws_size; (void)n_in; (void)out_size;

  hipMemsetAsync(ghist, 0, 768 * 4, stream);

  wconv_kernel<<<96, 256, 0, stream>>>(Wmn_dt, Wgn_dt, Ws_data, Wmn_td, Wgn_td, Ws_task, Wb);

  node_mfma_kernel<<<(N_DATA + 31) / 32, 256, 0, stream>>>(
      x_data, Wb, Wb + 16384, Wb + 32768,
      bmn_dt, bme_dt, bgn_dt, bge_dt, bs_data, bias_td,
      YG_dt, out, N_DATA);
  node_mfma_kernel<<<(N_TASK + 31) / 32, 256, 0, stream>>>(
      x_task, Wb + 3 * 16384, Wb + 4 * 16384, Wb + 5 * 16384,
      bmn_td, bme_td, bgn_td, bge_td, bs_task, bias_dt,
      YG_td, out + (size_t)N_DATA * D_DIM, N_TASK);

  hist0_kernel<<<256, 256, 0, stream>>>(dst_dt, dst_td, ghist, NBT, NB, E);
  bucket_scan_kernel<<<1, 256, 0, stream>>>(ghist, bbase, bcur, offs, NB, N_TOT);
  sort_a_kernel<<<(E + 4095) / 4096, 256, 0, stream>>>(
      src_dt, dst_dt, ef_dt, src_td, dst_td, ef_td, bcur, eA, NBT, NB, E);
  sort_b_kernel<<<NB, 256, 0, stream>>>(eA, bbase, offs, eB, NBT, N_TASK, N_TOT);

  gather_kernel<<<(N_TOT + 3) / 4, 256, 0, stream>>>(
      YG_dt, YG_td, offs, eB, Wme_dt, Wge_dt, Wme_td, Wge_td, out, N_TASK, N_DATA);
}